// Round 3
// baseline (871.199 us; speedup 1.0000x reference)
//
#include <hip/hip_runtime.h>
#include <hip/hip_bf16.h>

typedef unsigned short u16;
typedef __attribute__((ext_vector_type(8))) short bf16x8;
typedef __attribute__((ext_vector_type(2))) short s16x2;
typedef __attribute__((ext_vector_type(4))) float f32x4;

#define N_NODES 50000
#define EDGES 500000
#define WPT 31250     // 16-edge weight waves per type
#define SWPT 7813     // 64-edge scatter waves per type (ceil(500000/64))
#define NWAVES 3125   // node waves per type (50000/16)
#define NBLK 782      // ceil(NWAVES/4)

__device__ __forceinline__ u16 f2bf(float f) {
  return __builtin_bit_cast(u16, __float2bfloat16(f));
}
__device__ __forceinline__ float bf2f(u16 u) {
  return __builtin_bit_cast(float, ((unsigned)u) << 16);
}
__device__ __forceinline__ float bfe(bf16x8 v, int j) {
  return bf2f((u16)v[j]);
}

// packed bf16 atomic add (2 values at 4B-aligned address)
__device__ __forceinline__ void pk_atomic_bf16(u16* addr, float lo, float hi) {
#if __has_builtin(__builtin_amdgcn_global_atomic_fadd_v2bf16)
  s16x2 v;
  v[0] = (short)f2bf(lo);
  v[1] = (short)f2bf(hi);
  __builtin_amdgcn_global_atomic_fadd_v2bf16(
      (__attribute__((address_space(1))) s16x2*)addr, v);
#else
  unsigned* p = (unsigned*)addr;
  unsigned old = *p, assumed;
  do {
    assumed = old;
    float l2 = bf2f((u16)(assumed & 0xffff)) + lo;
    float h2 = bf2f((u16)(assumed >> 16)) + hi;
    unsigned nv = (unsigned)f2bf(l2) | ((unsigned)f2bf(h2) << 16);
    old = atomicCAS(p, assumed, nv);
  } while (old != assumed);
#endif
}

// ---------------------------------------------------------------------------
// weights -> bf16 tables (9 x 128x128 row-major), PLUS msgX zeroing
// 0 Wp, 1 Wc, 2 W1a, 3 W1b, 4 W1c, 5 Wrel_ab, 6 Wroot_ab, 7 Wrel_ba, 8 Wroot_ba
// ---------------------------------------------------------------------------
__global__ __launch_bounds__(256) void prep_weights_zero(
    const float* __restrict__ Wp, const float* __restrict__ Wc,
    const float* __restrict__ W1,
    const float* __restrict__ Wrel_ab, const float* __restrict__ Wroot_ab,
    const float* __restrict__ Wrel_ba, const float* __restrict__ Wroot_ba,
    u16* __restrict__ out, u16* __restrict__ msg)
{
  if (blockIdx.x >= 576) {
    // zero 2 * N_NODES * 128 bf16 = 12.8M u16, 8 per thread, 6250 blocks
    size_t t = (size_t)(blockIdx.x - 576) * 256 + threadIdx.x;
    bf16x8 z = {0, 0, 0, 0, 0, 0, 0, 0};
    *(bf16x8*)(msg + t * 8) = z;
    return;
  }
  int tid = blockIdx.x * 256 + threadIdx.x;  // 9*16384
  int m = tid >> 14;
  int idx = tid & 16383;
  int r = idx >> 7;
  int c = idx & 127;
  float val;
  switch (m) {
    case 0: val = Wp[r * 128 + c]; break;
    case 1: val = Wc[r * 128 + c]; break;
    case 2: val = W1[r * 384 + c]; break;
    case 3: val = W1[r * 384 + 128 + c]; break;
    case 4: val = W1[r * 384 + 256 + c]; break;
    case 5: val = Wrel_ab[r * 128 + c]; break;
    case 6: val = Wroot_ab[r * 128 + c]; break;
    case 7: val = Wrel_ba[r * 128 + c]; break;
    default: val = Wroot_ba[r * 128 + c]; break;
  }
  out[tid] = f2bf(val);
}

// ---------------------------------------------------------------------------
// Fused encoder + x cast, both node sets in one dispatch (grid 2*NBLK):
//   u = lrelu(x@Wp^T+bp) @ W1a^T + b1   (b1 folded in)
//   v = lrelu(x@Wc^T+bc) @ W1b^T
// ---------------------------------------------------------------------------
__global__ __launch_bounds__(256) void encoder2(
    const float* __restrict__ xa, const float* __restrict__ xb,
    const u16* __restrict__ Wp_b, const float* __restrict__ bp,
    const u16* __restrict__ Wc_b, const float* __restrict__ bc,
    const u16* __restrict__ W1a_b, const float* __restrict__ b1,
    const u16* __restrict__ W1b_b,
    u16* __restrict__ xa_bf, u16* __restrict__ xb_bf,
    u16* __restrict__ u_a, u16* __restrict__ v_a,
    u16* __restrict__ u_b, u16* __restrict__ v_b)
{
  __shared__ u16 tile[4][2176];   // 16 x pitch 136 bf16, per wave
  int widx = threadIdx.x >> 6;
  int w = blockIdx.x * 4 + widx;         // 0 .. 2*4*NBLK-1
  int type = (w >= NBLK * 4) ? 1 : 0;
  int nw = w - type * NBLK * 4;
  if (nw >= NWAVES) nw = NWAVES - 1;     // clamp (dup work; per-wave tile, safe)
  const float* x = type ? xb : xa;
  u16* xbf_out = type ? xb_bf : xa_bf;
  u16* u_out = type ? u_b : u_a;
  u16* v_out = type ? v_b : v_a;
  int row0 = nw * 16;
  int lane = threadIdx.x & 63;
  int col = lane & 15;
  int quad = lane >> 4;
  u16* tl = tile[widx];

  bf16x8 af[4];
#pragma unroll
  for (int ks = 0; ks < 4; ks++) {
    const float* xp = x + (size_t)(row0 + col) * 128 + ks * 32 + quad * 8;
    f32x4 lo = *(const f32x4*)xp;
    f32x4 hi = *(const f32x4*)(xp + 4);
    bf16x8 o;
#pragma unroll
    for (int j = 0; j < 4; j++) {
      o[j]     = (short)f2bf(lo[j]);
      o[j + 4] = (short)f2bf(hi[j]);
    }
    af[ks] = o;
    *(bf16x8*)(xbf_out + (size_t)(row0 + col) * 128 + ks * 32 + quad * 8) = o;
  }

  f32x4 zero = {0.f, 0.f, 0.f, 0.f};

  for (int chain = 0; chain < 2; chain++) {
    const u16* Wenc = chain ? Wc_b : Wp_b;
    const float* benc = chain ? bc : bp;
    const u16* Wmix = chain ? W1b_b : W1a_b;
    const float* bmix = chain ? nullptr : b1;
    u16* outp = chain ? v_out : u_out;

    f32x4 acc[8];
#pragma unroll
    for (int nt = 0; nt < 8; nt++) acc[nt] = zero;
#pragma unroll
    for (int ks = 0; ks < 4; ks++) {
      const u16* wp = Wenc + col * 128 + ks * 32 + quad * 8;
#pragma unroll
      for (int nt = 0; nt < 8; nt++) {
        bf16x8 bf = *(const bf16x8*)(wp + nt * 2048);
        acc[nt] = __builtin_amdgcn_mfma_f32_16x16x32_bf16(af[ks], bf, acc[nt], 0, 0, 0);
      }
    }
    // per-wave tile: in-wave lgkmcnt ordering suffices, no barrier
#pragma unroll
    for (int nt = 0; nt < 8; nt++) {
      float be = benc[nt * 16 + col];
#pragma unroll
      for (int r = 0; r < 4; r++) {
        float v = acc[nt][r] + be;
        v = v > 0.f ? v : 0.01f * v;
        tl[(quad * 4 + r) * 136 + nt * 16 + col] = f2bf(v);
      }
    }
    bf16x8 a2[4];
#pragma unroll
    for (int ks = 0; ks < 4; ks++)
      a2[ks] = *(const bf16x8*)&tl[col * 136 + ks * 32 + quad * 8];

    f32x4 acc2[8];
#pragma unroll
    for (int nt = 0; nt < 8; nt++) acc2[nt] = zero;
#pragma unroll
    for (int ks = 0; ks < 4; ks++) {
      const u16* wp = Wmix + col * 128 + ks * 32 + quad * 8;
#pragma unroll
      for (int nt = 0; nt < 8; nt++) {
        bf16x8 bf = *(const bf16x8*)(wp + nt * 2048);
        acc2[nt] = __builtin_amdgcn_mfma_f32_16x16x32_bf16(a2[ks], bf, acc2[nt], 0, 0, 0);
      }
    }
#pragma unroll
    for (int nt = 0; nt < 8; nt++) {
      float bm = bmix ? bmix[nt * 16 + col] : 0.f;
#pragma unroll
      for (int r = 0; r < 4; r++)
        outp[(size_t)(row0 + quad * 4 + r) * 128 + nt * 16 + col] = f2bf(acc2[nt][r] + bm);
    }
  }
}

// ---------------------------------------------------------------------------
// out = msgX@Wrel^T + x@Wroot^T + brel + broot  (fp32 out), both types.
// ---------------------------------------------------------------------------
__global__ __launch_bounds__(256) void out_gemm2(
    const u16* __restrict__ xa_bf, const u16* __restrict__ xb_bf,
    const u16* __restrict__ msgX_a, const u16* __restrict__ msgX_b,
    const u16* __restrict__ Wrelba_b, const u16* __restrict__ Wrelab_b,
    const u16* __restrict__ Wrootba_b, const u16* __restrict__ Wrootab_b,
    const float* __restrict__ brel_ba, const float* __restrict__ broot_ba,
    const float* __restrict__ brel_ab, const float* __restrict__ broot_ab,
    float* __restrict__ out_a, float* __restrict__ out_b)
{
  int w = blockIdx.x * 4 + (threadIdx.x >> 6);
  int type = (w >= NBLK * 4) ? 1 : 0;
  int nw = w - type * NBLK * 4;
  if (nw >= NWAVES) return;
  const u16* xbf = type ? xb_bf : xa_bf;
  const u16* msg = type ? msgX_b : msgX_a;
  const u16* Wrel = type ? Wrelab_b : Wrelba_b;
  const u16* Wroot = type ? Wrootab_b : Wrootba_b;
  const float* brel = type ? brel_ab : brel_ba;
  const float* broot = type ? broot_ab : broot_ba;
  float* outp = type ? out_b : out_a;
  int row0 = nw * 16;
  int lane = threadIdx.x & 63;
  int col = lane & 15;
  int quad = lane >> 4;

  bf16x8 ax[4], am[4];
#pragma unroll
  for (int ks = 0; ks < 4; ks++) {
    ax[ks] = *(const bf16x8*)(xbf + (size_t)(row0 + col) * 128 + ks * 32 + quad * 8);
    am[ks] = *(const bf16x8*)(msg + (size_t)(row0 + col) * 128 + ks * 32 + quad * 8);
  }

  f32x4 zero = {0.f, 0.f, 0.f, 0.f};
  f32x4 acc[8];
#pragma unroll
  for (int nt = 0; nt < 8; nt++) acc[nt] = zero;
#pragma unroll
  for (int ks = 0; ks < 4; ks++) {
    const u16* wp1 = Wrel + col * 128 + ks * 32 + quad * 8;
    const u16* wp2 = Wroot + col * 128 + ks * 32 + quad * 8;
#pragma unroll
    for (int nt = 0; nt < 8; nt++) {
      bf16x8 b1f = *(const bf16x8*)(wp1 + nt * 2048);
      acc[nt] = __builtin_amdgcn_mfma_f32_16x16x32_bf16(am[ks], b1f, acc[nt], 0, 0, 0);
      bf16x8 b2f = *(const bf16x8*)(wp2 + nt * 2048);
      acc[nt] = __builtin_amdgcn_mfma_f32_16x16x32_bf16(ax[ks], b2f, acc[nt], 0, 0, 0);
    }
  }
#pragma unroll
  for (int nt = 0; nt < 8; nt++) {
    int c = nt * 16 + col;
    float b = brel[c] + broot[c];
#pragma unroll
    for (int r = 0; r < 4; r++)
      outp[(size_t)(row0 + quad * 4 + r) * 128 + c] = acc[nt][r] + b;
  }
}

// ---------------------------------------------------------------------------
// Edge WEIGHT kernel (round-0 structure minus the atomic scatter tail).
// Computes w_e = sigmoid(W2 . relu(t+u+v) + b2) for 16 edges per wave and
// stores the scalar to wout[e]. No msgX traffic here.
// ---------------------------------------------------------------------------
__global__ __launch_bounds__(256) void edge_w(
    const u16* __restrict__ xa_bf, const u16* __restrict__ xb_bf,
    const int* __restrict__ ei_ab, const int* __restrict__ ei_ba,
    const u16* __restrict__ W1c,
    const u16* __restrict__ u_a, const u16* __restrict__ v_a,
    const u16* __restrict__ u_b, const u16* __restrict__ v_b,
    const float* __restrict__ W2, const float* __restrict__ b2p,
    float* __restrict__ w_ab, float* __restrict__ w_ba)
{
  __shared__ u16 tld[4][2176];   // 16 x pitch 136 bf16, per wave (17.4 KB)
  int widx = threadIdx.x >> 6;
  int w = blockIdx.x * 4 + widx;   // 0..62499
  int type = (w >= WPT) ? 1 : 0;
  int e0 = (w - type * WPT) * 16;
  const u16* xs = type ? xb_bf : xa_bf;
  const u16* xd = type ? xa_bf : xb_bf;
  const int* ei = type ? ei_ba : ei_ab;
  const u16* uT = type ? u_b : u_a;
  const u16* vT = type ? v_a : v_b;
  float* wout   = type ? w_ba : w_ab;

  int lane = threadIdx.x & 63;
  int col = lane & 15;
  int quad = lane >> 4;

  int em = e0 + col;
  int si = ei[em];
  int di = ei[EDGES + em];

  // epilogue edge ids (issued now so u/v gathers can start early)
  int e = e0 + (lane >> 2);
  int s2 = ei[e];
  int d2 = ei[EDGES + e];
  int c0 = (lane & 3) * 32;

  // x gathers (col-layout) — feed the MFMA chain
  bf16x8 af[4];
  bf16x8 d8[4];
#pragma unroll
  for (int ks = 0; ks < 4; ks++) {
    af[ks] = *(const bf16x8*)(xs + (size_t)si * 128 + ks * 32 + quad * 8);
    d8[ks] = *(const bf16x8*)(xd + (size_t)di * 128 + ks * 32 + quad * 8);
  }

  // u/v gathers (edge-major layout) — consumed in the epilogue
  const u16* urow = uT + (size_t)s2 * 128 + c0;
  const u16* vrow = vT + (size_t)d2 * 128 + c0;
  bf16x8 UU[4], VV[4];
#pragma unroll
  for (int k = 0; k < 4; k++) {
    UU[k] = *(const bf16x8*)(urow + k * 8);
    VV[k] = *(const bf16x8*)(vrow + k * 8);
  }

  // |par - cld| -> 32 MFMAs (t = d @ W1c^T)
  f32x4 zero = {0.f, 0.f, 0.f, 0.f};
  f32x4 acc[8];
#pragma unroll
  for (int nt = 0; nt < 8; nt++) acc[nt] = zero;
#pragma unroll
  for (int ks = 0; ks < 4; ks++) {
    bf16x8 df;
#pragma unroll
    for (int j = 0; j < 8; j++)
      df[j] = (short)f2bf(__builtin_fabsf(bfe(af[ks], j) - bfe(d8[ks], j)));
    const u16* wp = W1c + col * 128 + ks * 32 + quad * 8;
#pragma unroll
    for (int nt = 0; nt < 8; nt++) {
      bf16x8 bf = *(const bf16x8*)(wp + nt * 2048);
      acc[nt] = __builtin_amdgcn_mfma_f32_16x16x32_bf16(df, bf, acc[nt], 0, 0, 0);
    }
  }

  u16* tl = tld[widx];
#pragma unroll
  for (int nt = 0; nt < 8; nt++)
#pragma unroll
    for (int r = 0; r < 4; r++)
      tl[(quad * 4 + r) * 136 + nt * 16 + col] = f2bf(acc[nt][r]);

  // edge-major epilogue: w = sigmoid(W2 . relu(t + u + v) + b2)
  const u16* trow = &tl[(lane >> 2) * 136 + c0];
  float p = 0.f;
#pragma unroll
  for (int k = 0; k < 4; k++) {
    bf16x8 tt = *(const bf16x8*)(trow + k * 8);
    f32x4 w0 = *(const f32x4*)(W2 + c0 + k * 8);
    f32x4 w1 = *(const f32x4*)(W2 + c0 + k * 8 + 4);
#pragma unroll
    for (int j = 0; j < 4; j++) {
      float q0 = bfe(tt, j) + bfe(UU[k], j) + bfe(VV[k], j);
      if (q0 > 0.f) p += q0 * w0[j];
      float q1 = bfe(tt, j + 4) + bfe(UU[k], j + 4) + bfe(VV[k], j + 4);
      if (q1 > 0.f) p += q1 * w1[j];
    }
  }
  p += __shfl_xor(p, 1, 64);
  p += __shfl_xor(p, 2, 64);
  float wgt = 1.f / (1.f + __expf(-(p + b2p[0])));

  if ((lane & 3) == 0) wout[e] = wgt;   // 16 consecutive dwords per wave
}

// ---------------------------------------------------------------------------
// Edge SCATTER kernel: high-occupancy (no LDS, ~32 VGPR), 64 edges per wave.
// Per edge: one coalesced 256B row gather of x_src + one pk-atomic row add
// into msgX[dst]. Edges are dispatch-ordered consecutive (round-0 locality).
// ---------------------------------------------------------------------------
__global__ __launch_bounds__(256) void edge_scatter(
    const u16* __restrict__ xa_bf, const u16* __restrict__ xb_bf,
    const int* __restrict__ ei_ab, const int* __restrict__ ei_ba,
    const float* __restrict__ w_ab, const float* __restrict__ w_ba,
    u16* __restrict__ msgX_a, u16* __restrict__ msgX_b)
{
  int wv = blockIdx.x * 4 + (threadIdx.x >> 6);
  int lane = threadIdx.x & 63;
  int type = (wv >= SWPT) ? 1 : 0;
  int lw = wv - type * SWPT;
  if (lw >= SWPT) return;               // guard the 2 pad waves
  int e0 = lw * 64;
  if (e0 >= EDGES) return;
  const u16* xs = type ? xb_bf : xa_bf;
  const int* ei = type ? ei_ba : ei_ab;
  const float* wE = type ? w_ba : w_ab;
  u16* msgX = type ? msgX_a : msgX_b;

  int eL = e0 + lane;
  bool ok = eL < EDGES;
  int sv = ok ? ei[eL] : 0;
  int dv = ok ? ei[EDGES + eL] : 0;
  float wl = ok ? wE[eL] : 0.f;

  int nE = EDGES - e0;
  if (nE >= 64) {
#pragma unroll 8
    for (int j = 0; j < 64; j++) {
      float wr = __shfl(wl, j, 64);
      int sr = __shfl(sv, j, 64);
      int dr = __shfl(dv, j, 64);
      unsigned xv = *(const unsigned*)(xs + (size_t)sr * 128 + lane * 2);
      pk_atomic_bf16(msgX + (size_t)dr * 128 + lane * 2,
                     wr * bf2f((u16)(xv & 0xffff)),
                     wr * bf2f((u16)(xv >> 16)));
    }
  } else {
    for (int j = 0; j < nE; j++) {
      float wr = __shfl(wl, j, 64);
      int sr = __shfl(sv, j, 64);
      int dr = __shfl(dv, j, 64);
      unsigned xv = *(const unsigned*)(xs + (size_t)sr * 128 + lane * 2);
      pk_atomic_bf16(msgX + (size_t)dr * 128 + lane * 2,
                     wr * bf2f((u16)(xv & 0xffff)),
                     wr * bf2f((u16)(xv >> 16)));
    }
  }
}

// ---------------------------------------------------------------------------
extern "C" void kernel_launch(void* const* d_in, const int* in_sizes, int n_in,
                              void* d_out, int out_size, void* d_ws, size_t ws_size,
                              hipStream_t stream) {
  const float* x_a      = (const float*)d_in[0];
  const float* x_b      = (const float*)d_in[1];
  const float* Wp       = (const float*)d_in[2];
  const float* bp       = (const float*)d_in[3];
  const float* Wc       = (const float*)d_in[4];
  const float* bc       = (const float*)d_in[5];
  const float* W1       = (const float*)d_in[6];
  const float* b1       = (const float*)d_in[7];
  const float* W2       = (const float*)d_in[8];
  const float* b2       = (const float*)d_in[9];
  const float* Wrel_ab  = (const float*)d_in[10];
  const float* brel_ab  = (const float*)d_in[11];
  const float* Wroot_ab = (const float*)d_in[12];
  const float* broot_ab = (const float*)d_in[13];
  const float* Wrel_ba  = (const float*)d_in[14];
  const float* brel_ba  = (const float*)d_in[15];
  const float* Wroot_ba = (const float*)d_in[16];
  const float* broot_ba = (const float*)d_in[17];
  const int*   ei_ab    = (const int*)d_in[18];
  const int*   ei_ba    = (const int*)d_in[19];

  char* ws = (char*)d_ws;
  u16* Wb        = (u16*)ws;               // 9*16384*2 B
  u16* Wp_b      = Wb + 0 * 16384;
  u16* Wc_b      = Wb + 1 * 16384;
  u16* W1a_b     = Wb + 2 * 16384;
  u16* W1b_b     = Wb + 3 * 16384;
  u16* W1c_b     = Wb + 4 * 16384;
  u16* Wrelab_b  = Wb + 5 * 16384;
  u16* Wrootab_b = Wb + 6 * 16384;
  u16* Wrelba_b  = Wb + 7 * 16384;
  u16* Wrootba_b = Wb + 8 * 16384;

  // 12.8 MB bf16 node tables
  u16* xa_bf   = (u16*)(ws + 1048576);
  u16* xb_bf   = (u16*)(ws + 13848576);
  u16* u_a     = (u16*)(ws + 26648576);
  u16* v_a     = (u16*)(ws + 39448576);
  u16* u_b     = (u16*)(ws + 52248576);
  u16* v_b     = (u16*)(ws + 65048576);
  u16* msgX_a  = (u16*)(ws + 77848576);    // contiguous pair, 25.6 MB total
  u16* msgX_b  = (u16*)(ws + 90648576);

  float* out_a = (float*)d_out;
  float* out_b = out_a + (size_t)N_NODES * 128;

  // per-edge weight scratch lives in d_out (fully overwritten by out_gemm2
  // afterwards — stream order guarantees edge_scatter reads it first)
  float* w_ab = (float*)d_out;             // 2 MB
  float* w_ba = w_ab + EDGES;              // 2 MB

  // 1. weights -> bf16 + msgX zeroing (576 weight blocks + 6250 zero blocks)
  prep_weights_zero<<<6826, 256, 0, stream>>>(Wp, Wc, W1, Wrel_ab, Wroot_ab,
                                              Wrel_ba, Wroot_ba, Wb, msgX_a);

  // 2. encoder + x fp32->bf16 cast fused
  encoder2<<<2 * NBLK, 256, 0, stream>>>(x_a, x_b, Wp_b, bp, Wc_b, bc,
                                         W1a_b, b1, W1b_b,
                                         xa_bf, xb_bf, u_a, v_a, u_b, v_b);

  // 3. edge weight pass (round-0 residency, no atomic tail)
  edge_w<<<15625, 256, 0, stream>>>(xa_bf, xb_bf, ei_ab, ei_ba, W1c_b,
                                    u_a, v_a, u_b, v_b,
                                    W2, b2, w_ab, w_ba);

  // 4. high-occupancy scatter pass (2*SWPT waves = 15626, 3907 blocks)
  edge_scatter<<<3907, 256, 0, stream>>>(xa_bf, xb_bf, ei_ab, ei_ba,
                                         w_ab, w_ba, msgX_a, msgX_b);

  // 5. output GEMM
  out_gemm2<<<2 * NBLK, 256, 0, stream>>>(xa_bf, xb_bf, msgX_a, msgX_b,
                                          Wrelba_b, Wrelab_b,
                                          Wrootba_b, Wrootab_b,
                                          brel_ba, broot_ba, brel_ab, broot_ab,
                                          out_a, out_b);
}

// Round 4
// 656.571 us; speedup vs baseline: 1.3269x; 1.3269x over previous
//
#include <hip/hip_runtime.h>
#include <hip/hip_bf16.h>

typedef unsigned short u16;
typedef __attribute__((ext_vector_type(8))) short bf16x8;
typedef __attribute__((ext_vector_type(2))) short s16x2;
typedef __attribute__((ext_vector_type(4))) float f32x4;

#define N_NODES 50000
#define EDGES 500000
#define WPT 31250     // 16-edge groups per type
#define EPB 2048      // persistent edge blocks per type-launch
#define EPW (EPB * 4) // persistent edge waves per type-launch (8192)
#define NWAVES 3125   // node waves per type (50000/16)
#define NBLK 782      // ceil(NWAVES/4)

__device__ __forceinline__ u16 f2bf(float f) {
  return __builtin_bit_cast(u16, __float2bfloat16(f));
}
__device__ __forceinline__ float bf2f(u16 u) {
  return __builtin_bit_cast(float, ((unsigned)u) << 16);
}
__device__ __forceinline__ float bfe(bf16x8 v, int j) {
  return bf2f((u16)v[j]);
}

// packed bf16 atomic add (2 values at 4B-aligned address)
__device__ __forceinline__ void pk_atomic_bf16(u16* addr, float lo, float hi) {
#if __has_builtin(__builtin_amdgcn_global_atomic_fadd_v2bf16)
  s16x2 v;
  v[0] = (short)f2bf(lo);
  v[1] = (short)f2bf(hi);
  __builtin_amdgcn_global_atomic_fadd_v2bf16(
      (__attribute__((address_space(1))) s16x2*)addr, v);
#else
  unsigned* p = (unsigned*)addr;
  unsigned old = *p, assumed;
  do {
    assumed = old;
    float l2 = bf2f((u16)(assumed & 0xffff)) + lo;
    float h2 = bf2f((u16)(assumed >> 16)) + hi;
    unsigned nv = (unsigned)f2bf(l2) | ((unsigned)f2bf(h2) << 16);
    old = atomicCAS(p, assumed, nv);
  } while (old != assumed);
#endif
}

// ---------------------------------------------------------------------------
// weights -> bf16 tables (9 x 128x128 row-major), PLUS msgX zeroing
// 0 Wp, 1 Wc, 2 W1a, 3 W1b, 4 W1c, 5 Wrel_ab, 6 Wroot_ab, 7 Wrel_ba, 8 Wroot_ba
// ---------------------------------------------------------------------------
__global__ __launch_bounds__(256) void prep_weights_zero(
    const float* __restrict__ Wp, const float* __restrict__ Wc,
    const float* __restrict__ W1,
    const float* __restrict__ Wrel_ab, const float* __restrict__ Wroot_ab,
    const float* __restrict__ Wrel_ba, const float* __restrict__ Wroot_ba,
    u16* __restrict__ out, u16* __restrict__ msg)
{
  if (blockIdx.x >= 576) {
    // zero 2 * N_NODES * 128 bf16 = 12.8M u16, 8 per thread, 6250 blocks
    size_t t = (size_t)(blockIdx.x - 576) * 256 + threadIdx.x;
    bf16x8 z = {0, 0, 0, 0, 0, 0, 0, 0};
    *(bf16x8*)(msg + t * 8) = z;
    return;
  }
  int tid = blockIdx.x * 256 + threadIdx.x;  // 9*16384
  int m = tid >> 14;
  int idx = tid & 16383;
  int r = idx >> 7;
  int c = idx & 127;
  float val;
  switch (m) {
    case 0: val = Wp[r * 128 + c]; break;
    case 1: val = Wc[r * 128 + c]; break;
    case 2: val = W1[r * 384 + c]; break;
    case 3: val = W1[r * 384 + 128 + c]; break;
    case 4: val = W1[r * 384 + 256 + c]; break;
    case 5: val = Wrel_ab[r * 128 + c]; break;
    case 6: val = Wroot_ab[r * 128 + c]; break;
    case 7: val = Wrel_ba[r * 128 + c]; break;
    default: val = Wroot_ba[r * 128 + c]; break;
  }
  out[tid] = f2bf(val);
}

// ---------------------------------------------------------------------------
// Fused encoder + x cast, both node sets in one dispatch (grid 2*NBLK):
//   u = lrelu(x@Wp^T+bp) @ W1a^T + b1   (b1 folded in)
//   v = lrelu(x@Wc^T+bc) @ W1b^T
// ---------------------------------------------------------------------------
__global__ __launch_bounds__(256) void encoder2(
    const float* __restrict__ xa, const float* __restrict__ xb,
    const u16* __restrict__ Wp_b, const float* __restrict__ bp,
    const u16* __restrict__ Wc_b, const float* __restrict__ bc,
    const u16* __restrict__ W1a_b, const float* __restrict__ b1,
    const u16* __restrict__ W1b_b,
    u16* __restrict__ xa_bf, u16* __restrict__ xb_bf,
    u16* __restrict__ u_a, u16* __restrict__ v_a,
    u16* __restrict__ u_b, u16* __restrict__ v_b)
{
  __shared__ u16 tile[4][2176];   // 16 x pitch 136 bf16, per wave
  int widx = threadIdx.x >> 6;
  int w = blockIdx.x * 4 + widx;         // 0 .. 2*4*NBLK-1
  int type = (w >= NBLK * 4) ? 1 : 0;
  int nw = w - type * NBLK * 4;
  if (nw >= NWAVES) nw = NWAVES - 1;     // clamp (dup work; per-wave tile, safe)
  const float* x = type ? xb : xa;
  u16* xbf_out = type ? xb_bf : xa_bf;
  u16* u_out = type ? u_b : u_a;
  u16* v_out = type ? v_b : v_a;
  int row0 = nw * 16;
  int lane = threadIdx.x & 63;
  int col = lane & 15;
  int quad = lane >> 4;
  u16* tl = tile[widx];

  bf16x8 af[4];
#pragma unroll
  for (int ks = 0; ks < 4; ks++) {
    const float* xp = x + (size_t)(row0 + col) * 128 + ks * 32 + quad * 8;
    f32x4 lo = *(const f32x4*)xp;
    f32x4 hi = *(const f32x4*)(xp + 4);
    bf16x8 o;
#pragma unroll
    for (int j = 0; j < 4; j++) {
      o[j]     = (short)f2bf(lo[j]);
      o[j + 4] = (short)f2bf(hi[j]);
    }
    af[ks] = o;
    *(bf16x8*)(xbf_out + (size_t)(row0 + col) * 128 + ks * 32 + quad * 8) = o;
  }

  f32x4 zero = {0.f, 0.f, 0.f, 0.f};

  for (int chain = 0; chain < 2; chain++) {
    const u16* Wenc = chain ? Wc_b : Wp_b;
    const float* benc = chain ? bc : bp;
    const u16* Wmix = chain ? W1b_b : W1a_b;
    const float* bmix = chain ? nullptr : b1;
    u16* outp = chain ? v_out : u_out;

    f32x4 acc[8];
#pragma unroll
    for (int nt = 0; nt < 8; nt++) acc[nt] = zero;
#pragma unroll
    for (int ks = 0; ks < 4; ks++) {
      const u16* wp = Wenc + col * 128 + ks * 32 + quad * 8;
#pragma unroll
      for (int nt = 0; nt < 8; nt++) {
        bf16x8 bf = *(const bf16x8*)(wp + nt * 2048);
        acc[nt] = __builtin_amdgcn_mfma_f32_16x16x32_bf16(af[ks], bf, acc[nt], 0, 0, 0);
      }
    }
    // per-wave tile: in-wave lgkmcnt ordering suffices, no barrier
#pragma unroll
    for (int nt = 0; nt < 8; nt++) {
      float be = benc[nt * 16 + col];
#pragma unroll
      for (int r = 0; r < 4; r++) {
        float v = acc[nt][r] + be;
        v = v > 0.f ? v : 0.01f * v;
        tl[(quad * 4 + r) * 136 + nt * 16 + col] = f2bf(v);
      }
    }
    bf16x8 a2[4];
#pragma unroll
    for (int ks = 0; ks < 4; ks++)
      a2[ks] = *(const bf16x8*)&tl[col * 136 + ks * 32 + quad * 8];

    f32x4 acc2[8];
#pragma unroll
    for (int nt = 0; nt < 8; nt++) acc2[nt] = zero;
#pragma unroll
    for (int ks = 0; ks < 4; ks++) {
      const u16* wp = Wmix + col * 128 + ks * 32 + quad * 8;
#pragma unroll
      for (int nt = 0; nt < 8; nt++) {
        bf16x8 bf = *(const bf16x8*)(wp + nt * 2048);
        acc2[nt] = __builtin_amdgcn_mfma_f32_16x16x32_bf16(a2[ks], bf, acc2[nt], 0, 0, 0);
      }
    }
#pragma unroll
    for (int nt = 0; nt < 8; nt++) {
      float bm = bmix ? bmix[nt * 16 + col] : 0.f;
#pragma unroll
      for (int r = 0; r < 4; r++)
        outp[(size_t)(row0 + quad * 4 + r) * 128 + nt * 16 + col] = f2bf(acc2[nt][r] + bm);
    }
  }
}

// ---------------------------------------------------------------------------
// out = msgX@Wrel^T + x@Wroot^T + brel + broot  (fp32 out), both types.
// ---------------------------------------------------------------------------
__global__ __launch_bounds__(256) void out_gemm2(
    const u16* __restrict__ xa_bf, const u16* __restrict__ xb_bf,
    const u16* __restrict__ msgX_a, const u16* __restrict__ msgX_b,
    const u16* __restrict__ Wrelba_b, const u16* __restrict__ Wrelab_b,
    const u16* __restrict__ Wrootba_b, const u16* __restrict__ Wrootab_b,
    const float* __restrict__ brel_ba, const float* __restrict__ broot_ba,
    const float* __restrict__ brel_ab, const float* __restrict__ broot_ab,
    float* __restrict__ out_a, float* __restrict__ out_b)
{
  int w = blockIdx.x * 4 + (threadIdx.x >> 6);
  int type = (w >= NBLK * 4) ? 1 : 0;
  int nw = w - type * NBLK * 4;
  if (nw >= NWAVES) return;
  const u16* xbf = type ? xb_bf : xa_bf;
  const u16* msg = type ? msgX_b : msgX_a;
  const u16* Wrel = type ? Wrelab_b : Wrelba_b;
  const u16* Wroot = type ? Wrootab_b : Wrootba_b;
  const float* brel = type ? brel_ab : brel_ba;
  const float* broot = type ? broot_ab : broot_ba;
  float* outp = type ? out_b : out_a;
  int row0 = nw * 16;
  int lane = threadIdx.x & 63;
  int col = lane & 15;
  int quad = lane >> 4;

  bf16x8 ax[4], am[4];
#pragma unroll
  for (int ks = 0; ks < 4; ks++) {
    ax[ks] = *(const bf16x8*)(xbf + (size_t)(row0 + col) * 128 + ks * 32 + quad * 8);
    am[ks] = *(const bf16x8*)(msg + (size_t)(row0 + col) * 128 + ks * 32 + quad * 8);
  }

  f32x4 zero = {0.f, 0.f, 0.f, 0.f};
  f32x4 acc[8];
#pragma unroll
  for (int nt = 0; nt < 8; nt++) acc[nt] = zero;
#pragma unroll
  for (int ks = 0; ks < 4; ks++) {
    const u16* wp1 = Wrel + col * 128 + ks * 32 + quad * 8;
    const u16* wp2 = Wroot + col * 128 + ks * 32 + quad * 8;
#pragma unroll
    for (int nt = 0; nt < 8; nt++) {
      bf16x8 b1f = *(const bf16x8*)(wp1 + nt * 2048);
      acc[nt] = __builtin_amdgcn_mfma_f32_16x16x32_bf16(am[ks], b1f, acc[nt], 0, 0, 0);
      bf16x8 b2f = *(const bf16x8*)(wp2 + nt * 2048);
      acc[nt] = __builtin_amdgcn_mfma_f32_16x16x32_bf16(ax[ks], b2f, acc[nt], 0, 0, 0);
    }
  }
#pragma unroll
  for (int nt = 0; nt < 8; nt++) {
    int c = nt * 16 + col;
    float b = brel[c] + broot[c];
#pragma unroll
    for (int r = 0; r < 4; r++)
      outp[(size_t)(row0 + quad * 4 + r) * 128 + c] = acc[nt][r] + b;
  }
}

// ---------------------------------------------------------------------------
// Persistent TYPE-COHERENT fused edge kernel. Launched ONCE PER TYPE so the
// instantaneous cache working set is a single type's 4 node tables + 1 msgX
// (round-0 locality class), while residency is full persistent occupancy
// (round-1's proven 4 TB/s regime without its type-mixing sin).
// Body identical to the round-2 fused kernel; plain loop, no cross-iteration
// prefetch — TLP from residency does the hiding.
// ---------------------------------------------------------------------------
__global__ __launch_bounds__(256) void edge_fused_p(
    const u16* __restrict__ xs, const u16* __restrict__ xd,
    const int* __restrict__ ei,
    const u16* __restrict__ W1c,
    const u16* __restrict__ uT, const u16* __restrict__ vT,
    const float* __restrict__ W2, const float* __restrict__ b2p,
    u16* __restrict__ msgX)
{
  __shared__ u16 tld[4][2176];   // 16 x pitch 136 bf16, per wave (17.4 KB)
  int widx = threadIdx.x >> 6;
  int wt = blockIdx.x * 4 + widx;   // 0..EPW-1
  int lane = threadIdx.x & 63;
  int col = lane & 15;
  int quad = lane >> 4;
  int e4 = lane >> 2;
  int c0 = (lane & 3) * 32;
  u16* tl = tld[widx];

  for (int g = wt; g < WPT; g += EPW) {
    int e0 = g * 16;

    int em = e0 + col;
    int si = ei[em];
    int di = ei[EDGES + em];

    int e = e0 + e4;
    int s2 = ei[e];
    int d2 = ei[EDGES + e];

    // x gathers (col-layout) — feed the MFMA chain
    bf16x8 af[4];   // xs fragments — kept live for the scatter
    bf16x8 d8[4];
#pragma unroll
    for (int ks = 0; ks < 4; ks++) {
      af[ks] = *(const bf16x8*)(xs + (size_t)si * 128 + ks * 32 + quad * 8);
      d8[ks] = *(const bf16x8*)(xd + (size_t)di * 128 + ks * 32 + quad * 8);
    }

    // u/v gathers (edge-major layout) — consumed in the epilogue
    const u16* urow = uT + (size_t)s2 * 128 + c0;
    const u16* vrow = vT + (size_t)d2 * 128 + c0;
    bf16x8 UU[4], VV[4];
#pragma unroll
    for (int k = 0; k < 4; k++) {
      UU[k] = *(const bf16x8*)(urow + k * 8);
      VV[k] = *(const bf16x8*)(vrow + k * 8);
    }

    // |par - cld| -> 32 MFMAs (t = d @ W1c^T)
    f32x4 zero = {0.f, 0.f, 0.f, 0.f};
    f32x4 acc[8];
#pragma unroll
    for (int nt = 0; nt < 8; nt++) acc[nt] = zero;
#pragma unroll
    for (int ks = 0; ks < 4; ks++) {
      bf16x8 df;
#pragma unroll
      for (int j = 0; j < 8; j++)
        df[j] = (short)f2bf(__builtin_fabsf(bfe(af[ks], j) - bfe(d8[ks], j)));
      const u16* wp = W1c + col * 128 + ks * 32 + quad * 8;
#pragma unroll
      for (int nt = 0; nt < 8; nt++) {
        bf16x8 bf = *(const bf16x8*)(wp + nt * 2048);
        acc[nt] = __builtin_amdgcn_mfma_f32_16x16x32_bf16(df, bf, acc[nt], 0, 0, 0);
      }
    }

#pragma unroll
    for (int nt = 0; nt < 8; nt++)
#pragma unroll
      for (int r = 0; r < 4; r++)
        tl[(quad * 4 + r) * 136 + nt * 16 + col] = f2bf(acc[nt][r]);

    // edge-major epilogue: w = sigmoid(W2 . relu(t + u + v) + b2)
    const u16* trow = &tl[e4 * 136 + c0];
    float p = 0.f;
#pragma unroll
    for (int k = 0; k < 4; k++) {
      bf16x8 tt = *(const bf16x8*)(trow + k * 8);
      f32x4 w0 = *(const f32x4*)(W2 + c0 + k * 8);
      f32x4 w1 = *(const f32x4*)(W2 + c0 + k * 8 + 4);
#pragma unroll
      for (int j = 0; j < 4; j++) {
        float q0 = bfe(tt, j) + bfe(UU[k], j) + bfe(VV[k], j);
        if (q0 > 0.f) p += q0 * w0[j];
        float q1 = bfe(tt, j + 4) + bfe(UU[k], j + 4) + bfe(VV[k], j + 4);
        if (q1 > 0.f) p += q1 * w1[j];
      }
    }
    p += __shfl_xor(p, 1, 64);
    p += __shfl_xor(p, 2, 64);
    float wgt = 1.f / (1.f + __expf(-(p + b2p[0])));

    // xs frags -> same per-wave tile (t reads above are in-wave ordered)
#pragma unroll
    for (int ks = 0; ks < 4; ks++)
      *(bf16x8*)&tl[col * 136 + ks * 32 + quad * 8] = af[ks];

    // coalesced pk scatter
#pragma unroll
    for (int r = 0; r < 4; r++) {
      int src_lane = (quad * 4 + r) * 4;
      float wr = __shfl(wgt, src_lane, 64);
      int dr = __shfl(d2, src_lane, 64);
      u16* mrow = msgX + (size_t)dr * 128;
      const u16* xrow = &tl[(quad * 4 + r) * 136];
#pragma unroll
      for (int nt = 0; nt < 4; nt++) {
        int c = nt * 32 + col * 2;
        unsigned xv = *(const unsigned*)(xrow + c);
        pk_atomic_bf16(mrow + c, wr * bf2f((u16)(xv & 0xffff)),
                                 wr * bf2f((u16)(xv >> 16)));
      }
    }
  }
}

// ---------------------------------------------------------------------------
extern "C" void kernel_launch(void* const* d_in, const int* in_sizes, int n_in,
                              void* d_out, int out_size, void* d_ws, size_t ws_size,
                              hipStream_t stream) {
  const float* x_a      = (const float*)d_in[0];
  const float* x_b      = (const float*)d_in[1];
  const float* Wp       = (const float*)d_in[2];
  const float* bp       = (const float*)d_in[3];
  const float* Wc       = (const float*)d_in[4];
  const float* bc       = (const float*)d_in[5];
  const float* W1       = (const float*)d_in[6];
  const float* b1       = (const float*)d_in[7];
  const float* W2       = (const float*)d_in[8];
  const float* b2       = (const float*)d_in[9];
  const float* Wrel_ab  = (const float*)d_in[10];
  const float* brel_ab  = (const float*)d_in[11];
  const float* Wroot_ab = (const float*)d_in[12];
  const float* broot_ab = (const float*)d_in[13];
  const float* Wrel_ba  = (const float*)d_in[14];
  const float* brel_ba  = (const float*)d_in[15];
  const float* Wroot_ba = (const float*)d_in[16];
  const float* broot_ba = (const float*)d_in[17];
  const int*   ei_ab    = (const int*)d_in[18];
  const int*   ei_ba    = (const int*)d_in[19];

  char* ws = (char*)d_ws;
  u16* Wb        = (u16*)ws;               // 9*16384*2 B
  u16* Wp_b      = Wb + 0 * 16384;
  u16* Wc_b      = Wb + 1 * 16384;
  u16* W1a_b     = Wb + 2 * 16384;
  u16* W1b_b     = Wb + 3 * 16384;
  u16* W1c_b     = Wb + 4 * 16384;
  u16* Wrelab_b  = Wb + 5 * 16384;
  u16* Wrootab_b = Wb + 6 * 16384;
  u16* Wrelba_b  = Wb + 7 * 16384;
  u16* Wrootba_b = Wb + 8 * 16384;

  // 12.8 MB bf16 node tables
  u16* xa_bf   = (u16*)(ws + 1048576);
  u16* xb_bf   = (u16*)(ws + 13848576);
  u16* u_a     = (u16*)(ws + 26648576);
  u16* v_a     = (u16*)(ws + 39448576);
  u16* u_b     = (u16*)(ws + 52248576);
  u16* v_b     = (u16*)(ws + 65048576);
  u16* msgX_a  = (u16*)(ws + 77848576);    // contiguous pair, 25.6 MB total
  u16* msgX_b  = (u16*)(ws + 90648576);

  float* out_a = (float*)d_out;
  float* out_b = out_a + (size_t)N_NODES * 128;

  // 1. weights -> bf16 + msgX zeroing (576 weight blocks + 6250 zero blocks)
  prep_weights_zero<<<6826, 256, 0, stream>>>(Wp, Wc, W1, Wrel_ab, Wroot_ab,
                                              Wrel_ba, Wroot_ba, Wb, msgX_a);

  // 2. encoder + x fp32->bf16 cast fused
  encoder2<<<2 * NBLK, 256, 0, stream>>>(x_a, x_b, Wp_b, bp, Wc_b, bc,
                                         W1a_b, b1, W1b_b,
                                         xa_bf, xb_bf, u_a, v_a, u_b, v_b);

  // 3a. edge phase, type A->B (src=x_a, dst in B, msg into msgX_b)
  edge_fused_p<<<EPB, 256, 0, stream>>>(xa_bf, xb_bf, ei_ab, W1c_b,
                                        u_a, v_b, W2, b2, msgX_b);

  // 3b. edge phase, type B->A (src=x_b, dst in A, msg into msgX_a)
  edge_fused_p<<<EPB, 256, 0, stream>>>(xb_bf, xa_bf, ei_ba, W1c_b,
                                        u_b, v_a, W2, b2, msgX_a);

  // 4. output GEMM
  out_gemm2<<<2 * NBLK, 256, 0, stream>>>(xa_bf, xb_bf, msgX_a, msgX_b,
                                          Wrelba_b, Wrelab_b,
                                          Wrootba_b, Wrootab_b,
                                          brel_ba, broot_ba, brel_ab, broot_ab,
                                          out_a, out_b);
}